// Round 1
// baseline (1008.701 us; speedup 1.0000x reference)
//
#include <hip/hip_runtime.h>
#include <hip/hip_bf16.h>
#include <math.h>

// Problem constants (B,T,D,W,H) = (4096,1,4096,4,512)
#define B_  4096
#define D_  4096
#define W_  4
#define H_  512
#define NDW (D_*W_)   // 16384

typedef float  f32x4  __attribute__((ext_vector_type(4)));
typedef __bf16 bf16x8 __attribute__((ext_vector_type(8)));

__device__ __forceinline__ unsigned short f32_to_bf16(float f) {
    unsigned int u = __float_as_uint(f);
    u += 0x7fffu + ((u >> 16) & 1u);   // round-to-nearest-even
    return (unsigned short)(u >> 16);
}

__device__ __forceinline__ float silu_f(float v) {
    return v / (1.0f + __expf(-v));
}

// quad_perm DPP: lane ^1 and lane ^2 within each 4-lane group (VALU-only)
__device__ __forceinline__ float qxor1(float v) {
    return __int_as_float(__builtin_amdgcn_mov_dpp(__float_as_int(v), 0xB1, 0xF, 0xF, true));
}
__device__ __forceinline__ float qxor2(float v) {
    return __int_as_float(__builtin_amdgcn_mov_dpp(__float_as_int(v), 0x4E, 0xF, 0xF, true));
}

// ---------------------------------------------------------------- casts ----
__global__ void cast_g_kernel(const float* __restrict__ in,
                              unsigned short* __restrict__ out, int n4) {
    int i = blockIdx.x * blockDim.x + threadIdx.x;
    if (i >= n4) return;
    float4 v = ((const float4*)in)[i];
    ushort4 o;
    o.x = f32_to_bf16(v.x); o.y = f32_to_bf16(v.y);
    o.z = f32_to_bf16(v.z); o.w = f32_to_bf16(v.w);
    ((ushort4*)out)[i] = o;
}

// in: R x C f32 (row-major) -> out: C x R bf16 (row-major)
__global__ void transpose_cast_kernel(const float* __restrict__ in,
                                      unsigned short* __restrict__ out,
                                      int R, int C) {
    __shared__ unsigned short tile[64][65];
    const int r0 = blockIdx.y * 64;
    const int c0 = blockIdx.x * 64;
    const int tx = threadIdx.x & 63;
    const int ty = threadIdx.x >> 6;  // 0..3
#pragma unroll
    for (int rr = ty; rr < 64; rr += 4)
        tile[rr][tx] = f32_to_bf16(in[(size_t)(r0 + rr) * C + c0 + tx]);
    __syncthreads();
#pragma unroll
    for (int cc = ty; cc < 64; cc += 4)
        out[(size_t)(c0 + cc) * R + r0 + tx] = tile[tx][cc];
}

// ---------------------------------------------------------------- GEMM1 ----
// h = silu(g @ w1) -> bf16.  BM=BN=64, grid 8x64 = 512 blocks (2/CU).
// Double-buffered LDS, single barrier per K-step, XOR-swizzled tiles
// (source-swizzled for global_load_lds, swizzled ds_read).
__global__ __launch_bounds__(256, 2)
void gemm1_silu(const unsigned short* __restrict__ A,
                const unsigned short* __restrict__ Bt,
                unsigned short* __restrict__ Hout)
{
    // 2 bufs x (A 64x64 + B 64x64) bf16 = 32 KB
    __shared__ __align__(16) unsigned short smem[16384];

    const int tid  = threadIdx.x;
    const int wave = tid >> 6;
    const int lane = tid & 63;
    const int quad = lane >> 4;
    const int l16  = lane & 15;
    const int m0 = blockIdx.y * 64;
    const int n0 = blockIdx.x * 64;
    const int wm = (wave >> 1) * 32;   // wave: 32 rows
    const int wn = (wave & 1) * 32;    // wave: 32 cols

    f32x4 acc[2][2];
#pragma unroll
    for (int i = 0; i < 2; ++i)
#pragma unroll
        for (int j = 0; j < 2; ++j)
            acc[i][j] = (f32x4){0.f, 0.f, 0.f, 0.f};

#define STAGE1(bufOff, k0)                                                          \
    {                                                                               \
        _Pragma("unroll")                                                           \
        for (int r_ = 0; r_ < 2; ++r_) {                                            \
            const int flat_ = r_ * 256 + tid;                                       \
            const int row_  = flat_ >> 3;                                           \
            const int ch_   = (flat_ & 7) ^ (row_ & 7); /* source-side swizzle */   \
            const unsigned short* gA_ = A  + (size_t)(m0 + row_) * D_ + (k0) + ch_ * 8; \
            const unsigned short* gB_ = Bt + (size_t)(n0 + row_) * D_ + (k0) + ch_ * 8; \
            unsigned short* lA_ = smem + (bufOff) + (r_ * 256 + wave * 64) * 8;     \
            unsigned short* lB_ = smem + (bufOff) + 4096 + (r_ * 256 + wave * 64) * 8; \
            __builtin_amdgcn_global_load_lds(                                       \
                (const __attribute__((address_space(1))) void*)gA_,                 \
                (__attribute__((address_space(3))) void*)lA_, 16, 0, 0);            \
            __builtin_amdgcn_global_load_lds(                                       \
                (const __attribute__((address_space(1))) void*)gB_,                 \
                (__attribute__((address_space(3))) void*)lB_, 16, 0, 0);            \
        }                                                                           \
    }

#define COMP1(bufOff)                                                               \
    {                                                                               \
        const unsigned short* cA_ = smem + (bufOff);                                \
        const unsigned short* cB_ = smem + (bufOff) + 4096;                         \
        _Pragma("unroll")                                                           \
        for (int ks_ = 0; ks_ < 2; ++ks_) {                                         \
            const int sl_ = ks_ * 4 + quad;                                         \
            bf16x8 af_[2], bf_[2];                                                  \
            _Pragma("unroll")                                                       \
            for (int i_ = 0; i_ < 2; ++i_) {                                        \
                const int ra_ = wm + i_ * 16 + l16;                                 \
                const int rb_ = wn + i_ * 16 + l16;                                 \
                af_[i_] = *(const bf16x8*)(cA_ + ra_ * 64 + ((sl_ ^ (ra_ & 7)) * 8)); \
                bf_[i_] = *(const bf16x8*)(cB_ + rb_ * 64 + ((sl_ ^ (rb_ & 7)) * 8)); \
            }                                                                       \
            _Pragma("unroll")                                                       \
            for (int i_ = 0; i_ < 2; ++i_)                                          \
                _Pragma("unroll")                                                   \
                for (int j_ = 0; j_ < 2; ++j_)                                      \
                    acc[i_][j_] = __builtin_amdgcn_mfma_f32_16x16x32_bf16(          \
                        af_[i_], bf_[j_], acc[i_][j_], 0, 0, 0);                    \
        }                                                                           \
    }

    STAGE1(0, 0);
    __syncthreads();
    for (int t = 0; t < 63; ++t) {
        const int cur = (t & 1) * 8192;
        const int nxt = 8192 - cur;
        STAGE1(nxt, (t + 1) * 64);   // prefetch in flight during compute
        COMP1(cur);
        __syncthreads();             // one barrier per K-step
    }
    COMP1(8192);                     // t=63 (odd buffer), no barrier needed

    // C/D layout: col = lane&15, row = quad*4 + reg  [m89/m91]
#pragma unroll
    for (int i = 0; i < 2; ++i)
#pragma unroll
        for (int j = 0; j < 2; ++j) {
            const int col = n0 + wn + j * 16 + l16;
#pragma unroll
            for (int r = 0; r < 4; ++r) {
                const int row = m0 + wm + i * 16 + quad * 4 + r;
                Hout[(size_t)row * H_ + col] = f32_to_bf16(silu_f(acc[i][j][r]));
            }
        }
#undef STAGE1
#undef COMP1
}

// ------------------------------------------------- GEMM2 + conv (fused) ----
// flat_kernels tile = h @ w2 + b2 in AGPRs; conv consumed REGISTER-ONLY:
// col = n = 4*d + w maps w to adjacent lanes, so the sum over W=4 is a
// 4-lane quad reduction (2 DPP quad-perms). No LDS round-trip, no epilogue
// barriers. K-loop double-buffered (one barrier/step), tiles XOR-swizzled.
__global__ __launch_bounds__(256, 2)
void gemm2_conv(const unsigned short* __restrict__ A,   // h_bf  (B_ x H_)
                const unsigned short* __restrict__ Bt,  // w2t   (NDW x H_)
                const float* __restrict__ bias,
                const float* __restrict__ x,
                const float* __restrict__ cache,
                float* __restrict__ out,
                float* __restrict__ ncache)
{
    // 2 bufs x (A 128x64 + B 128x64) bf16 = 64 KB
    __shared__ __align__(16) unsigned short smem[32768];

    const int tid  = threadIdx.x;
    const int wave = tid >> 6;
    const int lane = tid & 63;
    const int quad = lane >> 4;
    const int l16  = lane & 15;

    // XCD-aware swizzle (grid 128x32 = 4096 blocks, 4096%8==0 -> bijective).
    // Column-major within each XCD chunk: 512 blocks/XCD = 16 full n-columns,
    // all sharing h_bf (4MB ~ one XCD L2) and a few w2t panels.
    const int bid = blockIdx.y * gridDim.x + blockIdx.x;   // 0..4095
    const int swz = (bid & 7) * 512 + (bid >> 3);
    const int m0 = (swz & 31) * 128;
    const int n0 = (swz >> 5) * 128;

    const int wm = (wave >> 1) * 64;
    const int wn = (wave & 1) * 64;

    f32x4 acc[4][4];
#pragma unroll
    for (int i = 0; i < 4; ++i)
#pragma unroll
        for (int j = 0; j < 4; ++j)
            acc[i][j] = (f32x4){0.f, 0.f, 0.f, 0.f};

#define STAGE2(bufOff, k0)                                                          \
    {                                                                               \
        _Pragma("unroll")                                                           \
        for (int r_ = 0; r_ < 4; ++r_) {                                            \
            const int flat_ = r_ * 256 + tid;                                       \
            const int row_  = flat_ >> 3;                                           \
            const int ch_   = (flat_ & 7) ^ (row_ & 7); /* source-side swizzle */   \
            const unsigned short* gA_ = A  + (size_t)(m0 + row_) * H_ + (k0) + ch_ * 8; \
            const unsigned short* gB_ = Bt + (size_t)(n0 + row_) * H_ + (k0) + ch_ * 8; \
            unsigned short* lA_ = smem + (bufOff) + (r_ * 256 + wave * 64) * 8;     \
            unsigned short* lB_ = smem + (bufOff) + 8192 + (r_ * 256 + wave * 64) * 8; \
            __builtin_amdgcn_global_load_lds(                                       \
                (const __attribute__((address_space(1))) void*)gA_,                 \
                (__attribute__((address_space(3))) void*)lA_, 16, 0, 0);            \
            __builtin_amdgcn_global_load_lds(                                       \
                (const __attribute__((address_space(1))) void*)gB_,                 \
                (__attribute__((address_space(3))) void*)lB_, 16, 0, 0);            \
        }                                                                           \
    }

#define COMP2(bufOff)                                                               \
    {                                                                               \
        const unsigned short* cA_ = smem + (bufOff);                                \
        const unsigned short* cB_ = smem + (bufOff) + 8192;                         \
        _Pragma("unroll")                                                           \
        for (int ks_ = 0; ks_ < 2; ++ks_) {                                         \
            const int sl_ = ks_ * 4 + quad;                                         \
            bf16x8 af_[4], bf_[4];                                                  \
            _Pragma("unroll")                                                       \
            for (int i_ = 0; i_ < 4; ++i_) {                                        \
                const int ra_ = wm + i_ * 16 + l16;                                 \
                const int rb_ = wn + i_ * 16 + l16;                                 \
                af_[i_] = *(const bf16x8*)(cA_ + ra_ * 64 + ((sl_ ^ (ra_ & 7)) * 8)); \
                bf_[i_] = *(const bf16x8*)(cB_ + rb_ * 64 + ((sl_ ^ (rb_ & 7)) * 8)); \
            }                                                                       \
            _Pragma("unroll")                                                       \
            for (int i_ = 0; i_ < 4; ++i_)                                          \
                _Pragma("unroll")                                                   \
                for (int j_ = 0; j_ < 4; ++j_)                                      \
                    acc[i_][j_] = __builtin_amdgcn_mfma_f32_16x16x32_bf16(          \
                        af_[i_], bf_[j_], acc[i_][j_], 0, 0, 0);                    \
        }                                                                           \
    }

    STAGE2(0, 0);
    __syncthreads();
#pragma unroll
    for (int t = 0; t < 7; ++t) {
        const int cur = (t & 1) * 16384;
        const int nxt = 16384 - cur;
        STAGE2(nxt, (t + 1) * 64);   // prefetch in flight during compute
        COMP2(cur);
        __syncthreads();             // one barrier per K-step
    }
    COMP2(16384);                    // t=7 (odd buffer)
#undef STAGE2
#undef COMP2

    // ---- register-only conv epilogue (no LDS, no barriers) ----
    // col = n0+wn+j*16+l16 = 4*d + w, with w = lane&3 -> the W=4 products of
    // one d live in one aligned 4-lane group; reduce with 2 quad-perm DPPs.
    const int w = l16 & 3;
#pragma unroll
    for (int j = 0; j < 4; ++j) {
        const int col = n0 + wn + j * 16 + l16;
        const float bv = bias[col];
        const int d = col >> 2;
#pragma unroll
        for (int i = 0; i < 4; ++i) {
#pragma unroll
            for (int r = 0; r < 4; ++r) {
                const int b = m0 + wm + i * 16 + quad * 4 + r;
                const size_t gi = (size_t)b * D_ + d;
                // new_cache[w] = cache[w+1] (w<3) else x  -- select address,
                // keep control flow uniform
                const float* src = (w < 3) ? (cache + gi * 4 + w + 1) : (x + gi);
                const float nc = *src;
                const float kv = acc[i][j][r] + bv;
                float p = nc * kv;
                p += qxor1(p);
                p += qxor2(p);          // all 4 lanes now hold sum over w
                ncache[gi * 4 + w] = nc;
                if (w == 0) out[gi] = silu_f(p);
            }
        }
    }
}

// ------------------------------------------------------------- launcher ----
extern "C" void kernel_launch(void* const* d_in, const int* in_sizes, int n_in,
                              void* d_out, int out_size, void* d_ws, size_t ws_size,
                              hipStream_t stream) {
    const float* x     = (const float*)d_in[0];
    const float* gin   = (const float*)d_in[1];
    const float* cache = (const float*)d_in[2];
    const float* w1    = (const float*)d_in[3];
    const float* w2    = (const float*)d_in[4];
    const float* b2    = (const float*)d_in[5];

    float* out    = (float*)d_out;                 // (B,1,D)
    float* ncache = out + (size_t)B_ * D_;         // (B,D,W)

    unsigned short* g_bf = (unsigned short*)d_ws;          // B*D bf16
    unsigned short* w1t  = g_bf + (size_t)B_ * D_;         // H*D bf16 (w1^T)
    unsigned short* w2t  = w1t + (size_t)H_ * D_;          // NDW*H bf16 (w2^T)
    unsigned short* h_bf = w2t + (size_t)NDW * H_;         // B*H bf16

    // 1) casts / transposes
    cast_g_kernel<<<(B_ * D_ / 4 + 255) / 256, 256, 0, stream>>>(gin, g_bf, B_ * D_ / 4);
    transpose_cast_kernel<<<dim3(H_ / 64, D_ / 64), 256, 0, stream>>>(w1, w1t, D_, H_);
    transpose_cast_kernel<<<dim3(NDW / 64, H_ / 64), 256, 0, stream>>>(w2, w2t, H_, NDW);

    // 2) h = silu(g @ w1): M=B, K=D, N=H  (512 blocks = 2/CU)
    gemm1_silu<<<dim3(H_ / 64, B_ / 64), 256, 0, stream>>>(g_bf, w1t, h_bf);

    // 3) fused: flat_kernels tile (h @ w2 + b2) -> conv -> out + new_cache
    gemm2_conv<<<dim3(NDW / 128, B_ / 128), 256, 0, stream>>>(
        h_bf, w2t, b2, x, cache, out, ncache);
}

// Round 2
// 744.826 us; speedup vs baseline: 1.3543x; 1.3543x over previous
//
#include <hip/hip_runtime.h>
#include <hip/hip_bf16.h>
#include <math.h>

// Problem constants (B,T,D,W,H) = (4096,1,4096,4,512)
#define B_  4096
#define D_  4096
#define W_  4
#define H_  512
#define NDW (D_*W_)   // 16384

typedef float  f32x4  __attribute__((ext_vector_type(4)));
typedef __bf16 bf16x8 __attribute__((ext_vector_type(8)));

__device__ __forceinline__ unsigned short f32_to_bf16(float f) {
    unsigned int u = __float_as_uint(f);
    u += 0x7fffu + ((u >> 16) & 1u);   // round-to-nearest-even
    return (unsigned short)(u >> 16);
}

__device__ __forceinline__ float silu_f(float v) {
    return v / (1.0f + __expf(-v));
}

// ---------------------------------------------------------------- casts ----
__global__ void cast_g_kernel(const float* __restrict__ in,
                              unsigned short* __restrict__ out, int n4) {
    int i = blockIdx.x * blockDim.x + threadIdx.x;
    if (i >= n4) return;
    float4 v = ((const float4*)in)[i];
    ushort4 o;
    o.x = f32_to_bf16(v.x); o.y = f32_to_bf16(v.y);
    o.z = f32_to_bf16(v.z); o.w = f32_to_bf16(v.w);
    ((ushort4*)out)[i] = o;
}

// in: R x C f32 (row-major) -> out: C x R bf16 (row-major)
__global__ void transpose_cast_kernel(const float* __restrict__ in,
                                      unsigned short* __restrict__ out,
                                      int R, int C) {
    __shared__ unsigned short tile[64][65];
    const int r0 = blockIdx.y * 64;
    const int c0 = blockIdx.x * 64;
    const int tx = threadIdx.x & 63;
    const int ty = threadIdx.x >> 6;  // 0..3
#pragma unroll
    for (int rr = ty; rr < 64; rr += 4)
        tile[rr][tx] = f32_to_bf16(in[(size_t)(r0 + rr) * C + c0 + tx]);
    __syncthreads();
#pragma unroll
    for (int cc = ty; cc < 64; cc += 4)
        out[(size_t)(c0 + cc) * R + r0 + tx] = tile[tx][cc];
}

// ---------------------------------------------------------------- GEMM1 ----
// h = silu(g @ w1) -> bf16.  BM=BN=64, grid 8x64 = 512 blocks (2/CU).
// Double-buffered LDS, single barrier per K-step, XOR-swizzled tiles.
__global__ __launch_bounds__(256, 2)
void gemm1_silu(const unsigned short* __restrict__ A,
                const unsigned short* __restrict__ Bt,
                unsigned short* __restrict__ Hout)
{
    // 2 bufs x (A 64x64 + B 64x64) bf16 = 32 KB
    __shared__ __align__(16) unsigned short smem[16384];

    const int tid  = threadIdx.x;
    const int wave = tid >> 6;
    const int lane = tid & 63;
    const int quad = lane >> 4;
    const int l16  = lane & 15;
    const int m0 = blockIdx.y * 64;
    const int n0 = blockIdx.x * 64;
    const int wm = (wave >> 1) * 32;   // wave: 32 rows
    const int wn = (wave & 1) * 32;    // wave: 32 cols

    f32x4 acc[2][2];
#pragma unroll
    for (int i = 0; i < 2; ++i)
#pragma unroll
        for (int j = 0; j < 2; ++j)
            acc[i][j] = (f32x4){0.f, 0.f, 0.f, 0.f};

#define STAGE1(bufOff, k0)                                                          \
    {                                                                               \
        _Pragma("unroll")                                                           \
        for (int r_ = 0; r_ < 2; ++r_) {                                            \
            const int flat_ = r_ * 256 + tid;                                       \
            const int row_  = flat_ >> 3;                                           \
            const int ch_   = (flat_ & 7) ^ (row_ & 7); /* source-side swizzle */   \
            const unsigned short* gA_ = A  + (size_t)(m0 + row_) * D_ + (k0) + ch_ * 8; \
            const unsigned short* gB_ = Bt + (size_t)(n0 + row_) * D_ + (k0) + ch_ * 8; \
            unsigned short* lA_ = smem + (bufOff) + (r_ * 256 + wave * 64) * 8;     \
            unsigned short* lB_ = smem + (bufOff) + 4096 + (r_ * 256 + wave * 64) * 8; \
            __builtin_amdgcn_global_load_lds(                                       \
                (const __attribute__((address_space(1))) void*)gA_,                 \
                (__attribute__((address_space(3))) void*)lA_, 16, 0, 0);            \
            __builtin_amdgcn_global_load_lds(                                       \
                (const __attribute__((address_space(1))) void*)gB_,                 \
                (__attribute__((address_space(3))) void*)lB_, 16, 0, 0);            \
        }                                                                           \
    }

#define COMP1(bufOff)                                                               \
    {                                                                               \
        const unsigned short* cA_ = smem + (bufOff);                                \
        const unsigned short* cB_ = smem + (bufOff) + 4096;                         \
        _Pragma("unroll")                                                           \
        for (int ks_ = 0; ks_ < 2; ++ks_) {                                         \
            const int sl_ = ks_ * 4 + quad;                                         \
            bf16x8 af_[2], bf_[2];                                                  \
            _Pragma("unroll")                                                       \
            for (int i_ = 0; i_ < 2; ++i_) {                                        \
                const int ra_ = wm + i_ * 16 + l16;                                 \
                const int rb_ = wn + i_ * 16 + l16;                                 \
                af_[i_] = *(const bf16x8*)(cA_ + ra_ * 64 + ((sl_ ^ (ra_ & 7)) * 8)); \
                bf_[i_] = *(const bf16x8*)(cB_ + rb_ * 64 + ((sl_ ^ (rb_ & 7)) * 8)); \
            }                                                                       \
            _Pragma("unroll")                                                       \
            for (int i_ = 0; i_ < 2; ++i_)                                          \
                _Pragma("unroll")                                                   \
                for (int j_ = 0; j_ < 2; ++j_)                                      \
                    acc[i_][j_] = __builtin_amdgcn_mfma_f32_16x16x32_bf16(          \
                        af_[i_], bf_[j_], acc[i_][j_], 0, 0, 0);                    \
        }                                                                           \
    }

    STAGE1(0, 0);
    __syncthreads();
    for (int t = 0; t < 63; ++t) {
        const int cur = (t & 1) * 8192;
        const int nxt = 8192 - cur;
        STAGE1(nxt, (t + 1) * 64);   // prefetch in flight during compute
        COMP1(cur);
        __syncthreads();             // one barrier per K-step
    }
    COMP1(8192);                     // t=63 (odd buffer), no barrier needed

    // C/D layout: col = lane&15, row = quad*4 + reg  [m89/m91]
#pragma unroll
    for (int i = 0; i < 2; ++i)
#pragma unroll
        for (int j = 0; j < 2; ++j) {
            const int col = n0 + wn + j * 16 + l16;
#pragma unroll
            for (int r = 0; r < 4; ++r) {
                const int row = m0 + wm + i * 16 + quad * 4 + r;
                Hout[(size_t)row * H_ + col] = f32_to_bf16(silu_f(acc[i][j][r]));
            }
        }
#undef STAGE1
#undef COMP1
}

// ------------------------------------------------- GEMM2 + conv (fused) ----
// flat_kernels tile = h @ w2 + b2 in AGPRs. K-loop: double-buffered,
// single barrier per K-step, XOR-swizzled tiles (bank-conflict-free,
// verified round 1). Epilogue: per-wave LDS transpose -- each wave spills
// its own 64x64 acc(+bias) into its PRIVATE 16KB quarter of smem
// (quad-XOR swizzle => <=2-way, free), then reads back f32x4 kernel values
// and runs the conv fully vectorized (16B cache/ncache per lane, coalesced).
// Only ONE barrier in the whole epilogue (to retire other waves' K-loop
// LDS reads); no inter-wave traffic, no idle waves.
__global__ __launch_bounds__(256, 2)
void gemm2_conv(const unsigned short* __restrict__ A,   // h_bf  (B_ x H_)
                const unsigned short* __restrict__ Bt,  // w2t   (NDW x H_)
                const float* __restrict__ bias,
                const float* __restrict__ x,
                const float* __restrict__ cache,
                float* __restrict__ out,
                float* __restrict__ ncache)
{
    // 2 bufs x (A 128x64 + B 128x64) bf16 = 64 KB; epilogue reuses all of it
    // as 4x (64x64 f32) per-wave scratch.
    __shared__ __align__(16) unsigned short smem[32768];

    const int tid  = threadIdx.x;
    const int wave = tid >> 6;
    const int lane = tid & 63;
    const int quad = lane >> 4;
    const int l16  = lane & 15;

    // XCD-aware swizzle (grid 4096 blocks, 4096%8==0 -> bijective).
    const int bid = blockIdx.y * gridDim.x + blockIdx.x;   // 0..4095
    const int swz = (bid & 7) * 512 + (bid >> 3);
    const int m0 = (swz & 31) * 128;
    const int n0 = (swz >> 5) * 128;

    const int wm = (wave >> 1) * 64;
    const int wn = (wave & 1) * 64;

    f32x4 acc[4][4];
#pragma unroll
    for (int i = 0; i < 4; ++i)
#pragma unroll
        for (int j = 0; j < 4; ++j)
            acc[i][j] = (f32x4){0.f, 0.f, 0.f, 0.f};

#define STAGE2(bufOff, k0)                                                          \
    {                                                                               \
        _Pragma("unroll")                                                           \
        for (int r_ = 0; r_ < 4; ++r_) {                                            \
            const int flat_ = r_ * 256 + tid;                                       \
            const int row_  = flat_ >> 3;                                           \
            const int ch_   = (flat_ & 7) ^ (row_ & 7); /* source-side swizzle */   \
            const unsigned short* gA_ = A  + (size_t)(m0 + row_) * H_ + (k0) + ch_ * 8; \
            const unsigned short* gB_ = Bt + (size_t)(n0 + row_) * H_ + (k0) + ch_ * 8; \
            unsigned short* lA_ = smem + (bufOff) + (r_ * 256 + wave * 64) * 8;     \
            unsigned short* lB_ = smem + (bufOff) + 8192 + (r_ * 256 + wave * 64) * 8; \
            __builtin_amdgcn_global_load_lds(                                       \
                (const __attribute__((address_space(1))) void*)gA_,                 \
                (__attribute__((address_space(3))) void*)lA_, 16, 0, 0);            \
            __builtin_amdgcn_global_load_lds(                                       \
                (const __attribute__((address_space(1))) void*)gB_,                 \
                (__attribute__((address_space(3))) void*)lB_, 16, 0, 0);            \
        }                                                                           \
    }

#define COMP2(bufOff)                                                               \
    {                                                                               \
        const unsigned short* cA_ = smem + (bufOff);                                \
        const unsigned short* cB_ = smem + (bufOff) + 8192;                         \
        _Pragma("unroll")                                                           \
        for (int ks_ = 0; ks_ < 2; ++ks_) {                                         \
            const int sl_ = ks_ * 4 + quad;                                         \
            bf16x8 af_[4], bf_[4];                                                  \
            _Pragma("unroll")                                                       \
            for (int i_ = 0; i_ < 4; ++i_) {                                        \
                const int ra_ = wm + i_ * 16 + l16;                                 \
                const int rb_ = wn + i_ * 16 + l16;                                 \
                af_[i_] = *(const bf16x8*)(cA_ + ra_ * 64 + ((sl_ ^ (ra_ & 7)) * 8)); \
                bf_[i_] = *(const bf16x8*)(cB_ + rb_ * 64 + ((sl_ ^ (rb_ & 7)) * 8)); \
            }                                                                       \
            _Pragma("unroll")                                                       \
            for (int i_ = 0; i_ < 4; ++i_)                                          \
                _Pragma("unroll")                                                   \
                for (int j_ = 0; j_ < 4; ++j_)                                      \
                    acc[i_][j_] = __builtin_amdgcn_mfma_f32_16x16x32_bf16(          \
                        af_[i_], bf_[j_], acc[i_][j_], 0, 0, 0);                    \
        }                                                                           \
    }

    STAGE2(0, 0);
    __syncthreads();
#pragma unroll
    for (int t = 0; t < 7; ++t) {
        const int cur = (t & 1) * 16384;
        const int nxt = 16384 - cur;
        STAGE2(nxt, (t + 1) * 64);   // prefetch in flight during compute
        COMP2(cur);
        __syncthreads();             // one barrier per K-step
    }
    COMP2(16384);                    // t=7 (odd buffer)
#undef STAGE2
#undef COMP2

    // ---- per-wave LDS-transpose conv epilogue ----
    __syncthreads();   // all waves done reading As/Bs -> reuse smem
    float* Ws = (float*)smem + wave * 4096;   // private 64x64 f32

    // spill acc(+bias): logical (row, col), col stored at col ^ (quad<<4)
    // (quad == (row>>2)&3) -> write banks 2-way max (free).
#pragma unroll
    for (int j = 0; j < 4; ++j) {
        const float bv = bias[n0 + wn + j * 16 + l16];
#pragma unroll
        for (int i = 0; i < 4; ++i)
#pragma unroll
            for (int r = 0; r < 4; ++r) {
                const int row = i * 16 + quad * 4 + r;
                const int col = (j * 16 + l16) ^ (quad << 4);
                Ws[row * 64 + col] = acc[i][j][r] + bv;
            }
    }
    // same-wave ds_write -> ds_read ordering handled by lgkmcnt (no barrier)

    const int dp    = lane & 15;               // d-group within wave's 64 cols
    const int r16   = lane >> 4;               // 0..3
    const int dbase = ((n0 + wn) >> 2) + dp;   // absolute d
#pragma unroll
    for (int rr = 0; rr < 16; ++rr) {
        const int row = rr * 4 + r16;          // 0..63  ((row>>2)&3 == rr&3)
        const int sw  = rr & 3;
        f32x4 k4 = *(const f32x4*)(Ws + row * 64 + ((dp * 4) ^ (sw << 4)));
        const int b = m0 + wm + row;
        const size_t gi = (size_t)b * D_ + dbase;   // (b,d) flat
        f32x4 c4 = ((const f32x4*)cache)[gi];
        float xv = x[gi];
        f32x4 nc = { c4.y, c4.z, c4.w, xv };
        float s = nc.x * k4.x + nc.y * k4.y + nc.z * k4.z + nc.w * k4.w;
        out[gi] = silu_f(s);
        ((f32x4*)ncache)[gi] = nc;
    }
}

// ------------------------------------------------------------- launcher ----
extern "C" void kernel_launch(void* const* d_in, const int* in_sizes, int n_in,
                              void* d_out, int out_size, void* d_ws, size_t ws_size,
                              hipStream_t stream) {
    const float* x     = (const float*)d_in[0];
    const float* gin   = (const float*)d_in[1];
    const float* cache = (const float*)d_in[2];
    const float* w1    = (const float*)d_in[3];
    const float* w2    = (const float*)d_in[4];
    const float* b2    = (const float*)d_in[5];

    float* out    = (float*)d_out;                 // (B,1,D)
    float* ncache = out + (size_t)B_ * D_;         // (B,D,W)

    unsigned short* g_bf = (unsigned short*)d_ws;          // B*D bf16
    unsigned short* w1t  = g_bf + (size_t)B_ * D_;         // H*D bf16 (w1^T)
    unsigned short* w2t  = w1t + (size_t)H_ * D_;          // NDW*H bf16 (w2^T)
    unsigned short* h_bf = w2t + (size_t)NDW * H_;         // B*H bf16

    // 1) casts / transposes
    cast_g_kernel<<<(B_ * D_ / 4 + 255) / 256, 256, 0, stream>>>(gin, g_bf, B_ * D_ / 4);
    transpose_cast_kernel<<<dim3(H_ / 64, D_ / 64), 256, 0, stream>>>(w1, w1t, D_, H_);
    transpose_cast_kernel<<<dim3(NDW / 64, H_ / 64), 256, 0, stream>>>(w2, w2t, H_, NDW);

    // 2) h = silu(g @ w1): M=B, K=D, N=H  (512 blocks = 2/CU)
    gemm1_silu<<<dim3(H_ / 64, B_ / 64), 256, 0, stream>>>(g_bf, w1t, h_bf);

    // 3) fused: flat_kernels tile (h @ w2 + b2) -> conv -> out + new_cache
    gemm2_conv<<<dim3(NDW / 128, B_ / 128), 256, 0, stream>>>(
        h_bf, w2t, b2, x, cache, out, ncache);
}